// Round 10
// baseline (169.446 us; speedup 1.0000x reference)
//
#include <hip/hip_runtime.h>

#define LEAKY(v) ((v) > 0.0f ? (v) : 0.2f * (v))

// ---- G1: GCN layer 1, gather form. One block per dest node c.
//          Single edge scan: LDS degree histogram (all nodes) + match list
//          (in-edges of c). Then agg1[c][j] = sum_m xw1(row_m)[j]*nrm + self.
//          No global atomics, no pre-zeroing. Writes deg[c]. ----
__global__ __launch_bounds__(256) void G1_gcn1(
        const int* __restrict__ row, const int* __restrict__ col,
        const float* __restrict__ x, const float* __restrict__ W1,
        float* __restrict__ deg, float* __restrict__ agg1, int n, int E) {
    __shared__ int ldeg[1000];
    __shared__ int mrow[128];
    __shared__ int mcnt;
    __shared__ float acc[32];
    const int c = blockIdx.x;
    const int tid = (int)threadIdx.x;

    for (int i = tid; i < n; i += 256) ldeg[i] = 0;
    if (tid == 0) mcnt = 0;
    if (tid < 32) acc[tid] = 0.0f;
    __syncthreads();

    for (int e = tid; e < E; e += 256) {
        int cc = col[e];
        atomicAdd(&ldeg[cc], 1);
        if (cc == c) {
            int slot = atomicAdd(&mcnt, 1);
            if (slot < 128) mrow[slot] = row[e];
        }
    }
    __syncthreads();

    const float dc = 1.0f / sqrtf((float)ldeg[c] + 1.0f);
    const int mtot = mcnt * 32;
    for (int idx = tid; idx < mtot; idx += 256) {
        int m = idx >> 5, j = idx & 31;
        int r = mrow[m];
        float nrm = (1.0f / sqrtf((float)ldeg[r] + 1.0f)) * dc;
        float v = x[r*6+3] * W1[96+j] + x[r*6+4] * W1[128+j] + x[r*6+5] * W1[160+j];
        atomicAdd(&acc[j], v * nrm);
    }
    __syncthreads();

    if (tid < 32) {
        int j = tid;
        float self = (x[c*6+3] * W1[96+j] + x[c*6+4] * W1[128+j] + x[c*6+5] * W1[160+j])
                   * (1.0f / ((float)ldeg[c] + 1.0f));
        agg1[c * 32 + j] = acc[j] + self;
    }
    if (tid == 32) deg[c] = (float)ldeg[c];
}

// ---- G2: GCN layer 2, gather form. One block per dest node c.
//          Edge scan for in-edges; per source r (incl. self), inline
//          h2row(r)[j] = sum_f leaky(agg1[r][f]+b1[f])*W2[f][j], scaled
//          by norm, accumulated in LDS. Writes agg2[c]. ----
__global__ __launch_bounds__(256) void G2_gcn2(
        const int* __restrict__ row, const int* __restrict__ col,
        const float* __restrict__ deg, const float* __restrict__ agg1,
        const float* __restrict__ b1, const float* __restrict__ W2,
        float* __restrict__ agg2, int n, int E) {
    __shared__ int mrow[128];
    __shared__ int mcnt;
    __shared__ float acc[32];
    const int c = blockIdx.x;
    const int tid = (int)threadIdx.x;

    if (tid == 0) mcnt = 0;
    if (tid < 32) acc[tid] = 0.0f;
    __syncthreads();

    for (int e = tid; e < E; e += 256) {
        if (col[e] == c) {
            int slot = atomicAdd(&mcnt, 1);
            if (slot < 128) mrow[slot] = row[e];
        }
    }
    __syncthreads();

    const float dc = 1.0f / sqrtf(deg[c] + 1.0f);
    const int mtot = (mcnt + 1) * 32;          // +1 slot = self-loop
    for (int idx = tid; idx < mtot; idx += 256) {
        int m = idx >> 5, j = idx & 31;
        int r; float nrm;
        if (m < mcnt) {
            r = mrow[m];
            nrm = (1.0f / sqrtf(deg[r] + 1.0f)) * dc;
        } else {
            r = c;
            nrm = 1.0f / (deg[c] + 1.0f);
        }
        const float* a = agg1 + r * 32;
        float s = 0.0f;
#pragma unroll
        for (int f = 0; f < 32; ++f) {
            float v = a[f] + b1[f];
            v = LEAKY(v);
            s += v * W2[f * 32 + j];
        }
        atomicAdd(&acc[j], s * nrm);
    }
    __syncthreads();

    if (tid < 32) agg2[c * 32 + tid] = acc[tid];
}

// ---- kD: conv1+conv2+conv3 block-slab with LDS staging (R5, verified) ----
__global__ __launch_bounds__(256) void kD_c3(const float* __restrict__ agg2,
        const float* __restrict__ b2,
        const float* __restrict__ k1w, const float* __restrict__ kb1,
        const float* __restrict__ k2w, const float* __restrict__ kb2,
        const float* __restrict__ k3w, const float* __restrict__ kb3,
        float* __restrict__ c3) {
    __shared__ float lc1[3][10][31];
    __shared__ float lc2[6][4][30];
    const int oh3 = blockIdx.x;
    const int tid = (int)threadIdx.x;

    for (int idx = tid; idx < 930; idx += 256) {
        int ci = idx / 310, rem = idx % 310;
        int hh = rem / 31, ow1 = rem % 31;
        int r0 = (4 * oh3 + hh) * 2;
        const float* kw = k1w + ci * 6;
        float v[4][2];
#pragma unroll
        for (int rr = 0; rr < 4; ++rr)
#pragma unroll
            for (int dc = 0; dc < 2; ++dc) {
                float u = agg2[(r0 + rr) * 32 + ow1 + dc] + b2[ow1 + dc];
                v[rr][dc] = LEAKY(u);
            }
        float a0 = v[0][0]*kw[0] + v[0][1]*kw[1] + v[1][0]*kw[2]
                 + v[1][1]*kw[3] + v[2][0]*kw[4] + v[2][1]*kw[5];
        float a1 = v[1][0]*kw[0] + v[1][1]*kw[1] + v[2][0]*kw[2]
                 + v[2][1]*kw[3] + v[3][0]*kw[4] + v[3][1]*kw[5];
        lc1[ci][hh][ow1] = fmaxf(fmaxf(a0, a1) + kb1[ci], 0.0f);
    }
    __syncthreads();

    for (int idx = tid; idx < 720; idx += 256) {
        int co2 = idx / 120, rem = idx % 120;
        int r = rem / 30, ow2 = rem % 30;
        float p0 = 0.0f, p1 = 0.0f;
#pragma unroll
        for (int ci = 0; ci < 3; ++ci) {
            const float* kw = k2w + (co2 * 3 + ci) * 6;
            const float* q0 = &lc1[ci][2*r][ow2];
            float r00 = q0[0],      r01 = q0[1];
            float r10 = q0[31],     r11 = q0[32];
            float r20 = q0[62],     r21 = q0[63];
            float r30 = q0[93],     r31 = q0[94];
            p0 += r00*kw[0] + r01*kw[1] + r10*kw[2] + r11*kw[3] + r20*kw[4] + r21*kw[5];
            p1 += r10*kw[0] + r11*kw[1] + r20*kw[2] + r21*kw[3] + r30*kw[4] + r31*kw[5];
        }
        lc2[co2][r][ow2] = fmaxf(fmaxf(p0, p1) + kb2[co2], 0.0f);
    }
    __syncthreads();

    if (tid < 87) {
        int co = tid / 29, ow3 = tid % 29;
        float A0 = 0.0f, A1 = 0.0f;
#pragma unroll
        for (int co2 = 0; co2 < 6; ++co2) {
            const float* kw3 = k3w + (co * 6 + co2) * 6;
            const float* q0 = &lc2[co2][0][ow3];
            float r00 = q0[0],      r01 = q0[1];
            float r10 = q0[30],     r11 = q0[31];
            float r20 = q0[60],     r21 = q0[61];
            float r30 = q0[90],     r31 = q0[91];
            A0 += r00*kw3[0] + r01*kw3[1] + r10*kw3[2] + r11*kw3[3] + r20*kw3[4] + r21*kw3[5];
            A1 += r10*kw3[0] + r11*kw3[1] + r20*kw3[2] + r21*kw3[3] + r30*kw3[4] + r31*kw3[5];
        }
        c3[(co * 123 + oh3) * 29 + ow3] = fmaxf(fmaxf(A0, A1) + kb3[co], 0.0f);
    }
}

// ---- kE: conv4 (redundant per block) into LDS, then FC1 rows (verified).
//          f1 written directly (fb1 included). Block 0 also zeroes out[64]
//          for kF's atomics. ----
__global__ __launch_bounds__(256) void kE_conv4_fc1(
        const float* __restrict__ c3, const float* __restrict__ k4,
        const float* __restrict__ kb4, const float* __restrict__ fw1,
        const float* __restrict__ fb1, float* __restrict__ f1,
        float* __restrict__ outz) {
    __shared__ __align__(16) float lc4[1680];
    const int Hin = 123, Win = 29, Wo = 28;
    if (blockIdx.x == 0 && threadIdx.x < 64) outz[threadIdx.x] = 0.0f;
    float kb = kb4[0];
    for (int t0 = (int)threadIdx.x; t0 < 1680; t0 += 256) {
        int ow = t0 % Wo; int oh = t0 / Wo;
        float a0 = 0.0f, a1 = 0.0f;
#pragma unroll
        for (int ci = 0; ci < 3; ++ci) {
            const float* q = c3 + (ci * Hin + 2 * oh) * Win + ow;
            const float* wp = k4 + ci * 6;
            float r00 = q[0],     r01 = q[1];
            float r10 = q[Win],   r11 = q[Win+1];
            float r20 = q[2*Win], r21 = q[2*Win+1];
            float r30 = q[3*Win], r31 = q[3*Win+1];
            a0 += r00*wp[0] + r01*wp[1] + r10*wp[2] + r11*wp[3] + r20*wp[4] + r21*wp[5];
            a1 += r10*wp[0] + r11*wp[1] + r20*wp[2] + r21*wp[3] + r30*wp[4] + r31*wp[5];
        }
        float m = fmaxf(a0, a1) + kb;
        lc4[t0] = fmaxf(m, 0.0f);
    }
    __syncthreads();
    int wv = (int)threadIdx.x >> 6, lane = (int)threadIdx.x & 63;
    int o = blockIdx.x * 4 + wv;
    const float4* wr = (const float4*)(fw1 + (size_t)o * 1680);
    const float4* vv = (const float4*)lc4;
    float s = 0.0f;
    for (int i = lane; i < 420; i += 64) {
        float4 a = vv[i], ww = wr[i];
        s += a.x*ww.x + a.y*ww.y + a.z*ww.z + a.w*ww.w;
    }
#pragma unroll
    for (int off = 32; off > 0; off >>= 1) s += __shfl_down(s, off, 64);
    if (lane == 0) f1[o] = s + fb1[o];
}

// ---- kF: FC2+FC3 (R6 version, verified; f1 already includes fb1).
//          out pre-zeroed by kE; block 0 adds fb3. ----
__global__ __launch_bounds__(256) void kF_fc23(const float* __restrict__ f1,
        const float* __restrict__ fw2, const float* __restrict__ fb2,
        const float* __restrict__ fw3, const float* __restrict__ fb3,
        float* __restrict__ out) {
    __shared__ float f2loc[16];
    int wv = (int)threadIdx.x >> 6, lane = (int)threadIdx.x & 63;
    int jbase = blockIdx.x * 16;
    const float4* vv = (const float4*)f1;
    for (int q = 0; q < 4; ++q) {
        int j = jbase + wv * 4 + q;
        const float4* wr = (const float4*)(fw2 + (size_t)j * 1024);
        float s = 0.0f;
#pragma unroll
        for (int i2 = 0; i2 < 4; ++i2) {
            float4 a = vv[lane + 64*i2], ww = wr[lane + 64*i2];
            s += a.x*ww.x + a.y*ww.y + a.z*ww.z + a.w*ww.w;
        }
#pragma unroll
        for (int off = 32; off > 0; off >>= 1) s += __shfl_down(s, off, 64);
        if (lane == 0) f2loc[wv * 4 + q] = s + fb2[j];
    }
    __syncthreads();
    for (int kk = 0; kk < 16; ++kk) {
        int k = wv * 16 + kk;
        float v = 0.0f;
        if (lane < 16) v = fw3[(size_t)k * 1024 + jbase + lane] * f2loc[lane];
#pragma unroll
        for (int off = 8; off > 0; off >>= 1) v += __shfl_down(v, off, 16);
        if (lane == 0) {
            if (blockIdx.x == 0) v += fb3[k];
            atomicAdd(&out[k], v);
        }
    }
}

extern "C" void kernel_launch(void* const* d_in, const int* in_sizes, int n_in,
                              void* d_out, int out_size, void* d_ws, size_t ws_size,
                              hipStream_t stream) {
    const float* x   = (const float*)d_in[0];
    const int*   ei  = (const int*)d_in[1];
    const float* W1  = (const float*)d_in[2];
    const float* b1  = (const float*)d_in[3];
    const float* W2  = (const float*)d_in[4];
    const float* b2  = (const float*)d_in[5];
    const float* k1  = (const float*)d_in[6];
    const float* kb1 = (const float*)d_in[7];
    const float* k2  = (const float*)d_in[8];
    const float* kb2 = (const float*)d_in[9];
    const float* k3  = (const float*)d_in[10];
    const float* kb3 = (const float*)d_in[11];
    const float* k4  = (const float*)d_in[12];
    const float* kb4 = (const float*)d_in[13];
    const float* fw1 = (const float*)d_in[14];
    const float* fb1 = (const float*)d_in[15];
    const float* fw2 = (const float*)d_in[16];
    const float* fb2 = (const float*)d_in[17];
    const float* fw3 = (const float*)d_in[18];
    const float* fb3 = (const float*)d_in[19];

    int n = in_sizes[0] / 6;       // 1000
    int E = in_sizes[1] / 2;       // 8000
    const int* row = ei;
    const int* col = ei + E;

    float* ws   = (float*)d_ws;
    float* deg  = ws;              // 1024 (fully written by G1)
    float* agg1 = ws + 1024;       // 32000 (fully written by G1)
    float* agg2 = agg1 + 32000;    // 32000 (fully written by G2)
    float* c3   = agg2 + 32000;    // 10704 (padded, 16B aligned)
    float* f1   = c3 + 10704;      // 1024 (fully written by kE)

    const int B = 256;

    G1_gcn1<<<n, B, 0, stream>>>(row, col, x, W1, deg, agg1, n, E);
    G2_gcn2<<<n, B, 0, stream>>>(row, col, deg, agg1, b1, W2, agg2, n, E);
    kD_c3<<<123, B, 0, stream>>>(agg2, b2, k1, kb1, k2, kb2, k3, kb3, c3);
    kE_conv4_fc1<<<256, B, 0, stream>>>(c3, k4, kb4, fw1, fb1, f1, (float*)d_out);
    kF_fc23<<<64, B, 0, stream>>>(f1, fw2, fb2, fw3, fb3, (float*)d_out);
}

// Round 11
// 164.428 us; speedup vs baseline: 1.0305x; 1.0305x over previous
//
#include <hip/hip_runtime.h>

#define LEAKY(v) ((v) > 0.0f ? (v) : 0.2f * (v))

// ---- k1: zero agg1/agg2, xw1 = x@W1 (features 3..5); block 0 builds deg
//          via single-block LDS histogram (replaces memset+global atomics). ----
__global__ __launch_bounds__(256) void k1_prep(const float* __restrict__ x,
                        const int* __restrict__ col, const float* __restrict__ W1,
                        float* __restrict__ deg,
                        float* __restrict__ aggs /*agg1,agg2 contiguous*/,
                        float* __restrict__ xw, int n, int E) {
    int T = blockIdx.x * 256 + (int)threadIdx.x;
    int NT = gridDim.x * 256;
    for (int i = T; i < 2 * n * 32; i += NT) aggs[i] = 0.0f;
    for (int t = T; t < n * 32; t += NT) {
        int j = t & 31, nn = t >> 5;
        xw[t] = x[nn*6+3] * W1[96+j]
              + x[nn*6+4] * W1[128+j]
              + x[nn*6+5] * W1[160+j];
    }
    if (blockIdx.x == 0) {
        __shared__ int ldeg[1024];
        int tid = (int)threadIdx.x;
        for (int i = tid; i < 1024; i += 256) ldeg[i] = 0;
        __syncthreads();
        for (int e = tid; e < E; e += 256) atomicAdd(&ldeg[col[e]], 1);
        __syncthreads();
        for (int i = tid; i < n; i += 256) deg[i] = (float)ldeg[i];
    }
}

// ---- scatter (VERBATIM R0, verified): agg[col] += xw[row]*norm incl self ----
__global__ void k_scatter(const float* __restrict__ xw, const float* __restrict__ deg,
                          const int* __restrict__ row, const int* __restrict__ col,
                          float* __restrict__ agg, int E, int n) {
    int tid = blockIdx.x * blockDim.x + threadIdx.x;
    int total = (E + n) * 32;
    if (tid >= total) return;
    int e = tid >> 5, j = tid & 31;
    int r, c; float nrm;
    if (e < E) {
        r = row[e]; c = col[e];
        nrm = (1.0f / sqrtf(deg[r] + 1.0f)) * (1.0f / sqrtf(deg[c] + 1.0f));
    } else {
        r = c = e - E;
        nrm = 1.0f / (deg[r] + 1.0f);
    }
    atomicAdd(&agg[c * 32 + j], xw[r * 32 + j] * nrm);
}

// ---- k3 (VERBATIM R0, verified): xw = leaky(agg1 + b1) @ W2 ----
__global__ void k3_xw2(const float* __restrict__ agg1, const float* __restrict__ b1,
                       const float* __restrict__ W2, float* __restrict__ xw, int n) {
    int tid = blockIdx.x * blockDim.x + threadIdx.x;
    if (tid >= n * 32) return;
    int j = tid & 31, nn = tid >> 5;
    const float* a = agg1 + nn * 32;
    float s = 0.0f;
#pragma unroll
    for (int f = 0; f < 32; ++f) {
        float v = a[f] + b1[f];
        v = LEAKY(v);
        s += v * W2[f * 32 + j];
    }
    xw[tid] = s;
}

// ---- kD: conv1+conv2+conv3 block-slab (VERBATIM R5, verified light) ----
__global__ __launch_bounds__(256) void kD_c3(const float* __restrict__ agg2,
        const float* __restrict__ b2,
        const float* __restrict__ k1w, const float* __restrict__ kb1,
        const float* __restrict__ k2w, const float* __restrict__ kb2,
        const float* __restrict__ k3w, const float* __restrict__ kb3,
        float* __restrict__ c3) {
    __shared__ float lc1[3][10][31];
    __shared__ float lc2[6][4][30];
    const int oh3 = blockIdx.x;
    const int tid = (int)threadIdx.x;

    for (int idx = tid; idx < 930; idx += 256) {
        int ci = idx / 310, rem = idx % 310;
        int hh = rem / 31, ow1 = rem % 31;
        int r0 = (4 * oh3 + hh) * 2;
        const float* kw = k1w + ci * 6;
        float v[4][2];
#pragma unroll
        for (int rr = 0; rr < 4; ++rr)
#pragma unroll
            for (int dc = 0; dc < 2; ++dc) {
                float u = agg2[(r0 + rr) * 32 + ow1 + dc] + b2[ow1 + dc];
                v[rr][dc] = LEAKY(u);
            }
        float a0 = v[0][0]*kw[0] + v[0][1]*kw[1] + v[1][0]*kw[2]
                 + v[1][1]*kw[3] + v[2][0]*kw[4] + v[2][1]*kw[5];
        float a1 = v[1][0]*kw[0] + v[1][1]*kw[1] + v[2][0]*kw[2]
                 + v[2][1]*kw[3] + v[3][0]*kw[4] + v[3][1]*kw[5];
        lc1[ci][hh][ow1] = fmaxf(fmaxf(a0, a1) + kb1[ci], 0.0f);
    }
    __syncthreads();

    for (int idx = tid; idx < 720; idx += 256) {
        int co2 = idx / 120, rem = idx % 120;
        int r = rem / 30, ow2 = rem % 30;
        float p0 = 0.0f, p1 = 0.0f;
#pragma unroll
        for (int ci = 0; ci < 3; ++ci) {
            const float* kw = k2w + (co2 * 3 + ci) * 6;
            const float* q0 = &lc1[ci][2*r][ow2];
            float r00 = q0[0],      r01 = q0[1];
            float r10 = q0[31],     r11 = q0[32];
            float r20 = q0[62],     r21 = q0[63];
            float r30 = q0[93],     r31 = q0[94];
            p0 += r00*kw[0] + r01*kw[1] + r10*kw[2] + r11*kw[3] + r20*kw[4] + r21*kw[5];
            p1 += r10*kw[0] + r11*kw[1] + r20*kw[2] + r21*kw[3] + r30*kw[4] + r31*kw[5];
        }
        lc2[co2][r][ow2] = fmaxf(fmaxf(p0, p1) + kb2[co2], 0.0f);
    }
    __syncthreads();

    if (tid < 87) {
        int co = tid / 29, ow3 = tid % 29;
        float A0 = 0.0f, A1 = 0.0f;
#pragma unroll
        for (int co2 = 0; co2 < 6; ++co2) {
            const float* kw3 = k3w + (co * 6 + co2) * 6;
            const float* q0 = &lc2[co2][0][ow3];
            float r00 = q0[0],      r01 = q0[1];
            float r10 = q0[30],     r11 = q0[31];
            float r20 = q0[60],     r21 = q0[61];
            float r30 = q0[90],     r31 = q0[91];
            A0 += r00*kw3[0] + r01*kw3[1] + r10*kw3[2] + r11*kw3[3] + r20*kw3[4] + r21*kw3[5];
            A1 += r10*kw3[0] + r11*kw3[1] + r20*kw3[2] + r21*kw3[3] + r30*kw3[4] + r31*kw3[5];
        }
        c3[(co * 123 + oh3) * 29 + ow3] = fmaxf(fmaxf(A0, A1) + kb3[co], 0.0f);
    }
}

// ---- k8 (VERBATIM R0, verified): conv4 redundant per block into LDS, then
//          FC1 rows. Block 0 also zeroes out[64] for kF's atomics. ----
__global__ __launch_bounds__(256) void k8_conv4_fc1(
        const float* __restrict__ c3, const float* __restrict__ k4,
        const float* __restrict__ kb4, const float* __restrict__ fw1,
        const float* __restrict__ fb1, float* __restrict__ f1,
        float* __restrict__ outz) {
    __shared__ __align__(16) float lc4[1680];
    const int Hin = 123, Win = 29, Wo = 28;
    if (blockIdx.x == 0 && threadIdx.x < 64) outz[threadIdx.x] = 0.0f;
    float kb = kb4[0];
    for (int t0 = (int)threadIdx.x; t0 < 1680; t0 += 256) {
        int ow = t0 % Wo; int oh = t0 / Wo;
        float a0 = 0.0f, a1 = 0.0f;
#pragma unroll
        for (int ci = 0; ci < 3; ++ci) {
            const float* q = c3 + (ci * Hin + 2 * oh) * Win + ow;
            const float* wp = k4 + ci * 6;
            float r00 = q[0],     r01 = q[1];
            float r10 = q[Win],   r11 = q[Win+1];
            float r20 = q[2*Win], r21 = q[2*Win+1];
            float r30 = q[3*Win], r31 = q[3*Win+1];
            a0 += r00*wp[0] + r01*wp[1] + r10*wp[2] + r11*wp[3] + r20*wp[4] + r21*wp[5];
            a1 += r10*wp[0] + r11*wp[1] + r20*wp[2] + r21*wp[3] + r30*wp[4] + r31*wp[5];
        }
        float m = fmaxf(a0, a1) + kb;
        lc4[t0] = fmaxf(m, 0.0f);
    }
    __syncthreads();
    int wv = (int)threadIdx.x >> 6, lane = (int)threadIdx.x & 63;
    int o = blockIdx.x * 4 + wv;
    const float4* wr = (const float4*)(fw1 + (size_t)o * 1680);
    const float4* vv = (const float4*)lc4;
    float s = 0.0f;
    for (int i = lane; i < 420; i += 64) {
        float4 a = vv[i], ww = wr[i];
        s += a.x*ww.x + a.y*ww.y + a.z*ww.z + a.w*ww.w;
    }
#pragma unroll
    for (int off = 32; off > 0; off >>= 1) s += __shfl_down(s, off, 64);
    if (lane == 0) f1[o] = s + fb1[o];
}

// ---- kF: FC2+FC3 merged (VERBATIM R10, verified; f1 includes fb1;
//          out pre-zeroed by k8; block 0 adds fb3). ----
__global__ __launch_bounds__(256) void kF_fc23(const float* __restrict__ f1,
        const float* __restrict__ fw2, const float* __restrict__ fb2,
        const float* __restrict__ fw3, const float* __restrict__ fb3,
        float* __restrict__ out) {
    __shared__ float f2loc[16];
    int wv = (int)threadIdx.x >> 6, lane = (int)threadIdx.x & 63;
    int jbase = blockIdx.x * 16;
    const float4* vv = (const float4*)f1;
    for (int q = 0; q < 4; ++q) {
        int j = jbase + wv * 4 + q;
        const float4* wr = (const float4*)(fw2 + (size_t)j * 1024);
        float s = 0.0f;
#pragma unroll
        for (int i2 = 0; i2 < 4; ++i2) {
            float4 a = vv[lane + 64*i2], ww = wr[lane + 64*i2];
            s += a.x*ww.x + a.y*ww.y + a.z*ww.z + a.w*ww.w;
        }
#pragma unroll
        for (int off = 32; off > 0; off >>= 1) s += __shfl_down(s, off, 64);
        if (lane == 0) f2loc[wv * 4 + q] = s + fb2[j];
    }
    __syncthreads();
    for (int kk = 0; kk < 16; ++kk) {
        int k = wv * 16 + kk;
        float v = 0.0f;
        if (lane < 16) v = fw3[(size_t)k * 1024 + jbase + lane] * f2loc[lane];
#pragma unroll
        for (int off = 8; off > 0; off >>= 1) v += __shfl_down(v, off, 16);
        if (lane == 0) {
            if (blockIdx.x == 0) v += fb3[k];
            atomicAdd(&out[k], v);
        }
    }
}

extern "C" void kernel_launch(void* const* d_in, const int* in_sizes, int n_in,
                              void* d_out, int out_size, void* d_ws, size_t ws_size,
                              hipStream_t stream) {
    const float* x   = (const float*)d_in[0];
    const int*   ei  = (const int*)d_in[1];
    const float* W1  = (const float*)d_in[2];
    const float* b1  = (const float*)d_in[3];
    const float* W2  = (const float*)d_in[4];
    const float* b2  = (const float*)d_in[5];
    const float* k1  = (const float*)d_in[6];
    const float* kb1 = (const float*)d_in[7];
    const float* k2  = (const float*)d_in[8];
    const float* kb2 = (const float*)d_in[9];
    const float* k3  = (const float*)d_in[10];
    const float* kb3 = (const float*)d_in[11];
    const float* k4  = (const float*)d_in[12];
    const float* kb4 = (const float*)d_in[13];
    const float* fw1 = (const float*)d_in[14];
    const float* fb1 = (const float*)d_in[15];
    const float* fw2 = (const float*)d_in[16];
    const float* fb2 = (const float*)d_in[17];
    const float* fw3 = (const float*)d_in[18];
    const float* fb3 = (const float*)d_in[19];

    int n = in_sizes[0] / 6;       // 1000
    int E = in_sizes[1] / 2;       // 8000
    const int* row = ei;
    const int* col = ei + E;

    float* ws   = (float*)d_ws;
    float* deg  = ws;              // 1024 (fully written by k1_prep block 0)
    float* agg1 = ws + 1024;       // 32000 (agg1+agg2 contiguous for zeroing)
    float* agg2 = agg1 + 32000;    // 32000
    float* xw   = agg2 + 32000;    // 32000
    float* c3   = xw + 32000;      // 10704 (padded, 16B aligned)
    float* f1   = c3 + 10704;      // 1024 (16B aligned)

    const int B = 256;
    int st = (E + n) * 32;

    k1_prep<<<256, B, 0, stream>>>(x, col, W1, deg, agg1, xw, n, E);
    k_scatter<<<(st + B - 1) / B, B, 0, stream>>>(xw, deg, row, col, agg1, E, n);
    k3_xw2<<<(n * 32 + B - 1) / B, B, 0, stream>>>(agg1, b1, W2, xw, n);
    k_scatter<<<(st + B - 1) / B, B, 0, stream>>>(xw, deg, row, col, agg2, E, n);
    kD_c3<<<123, B, 0, stream>>>(agg2, b2, k1, kb1, k2, kb2, k3, kb3, c3);
    k8_conv4_fc1<<<256, B, 0, stream>>>(c3, k4, kb4, fw1, fb1, f1, (float*)d_out);
    kF_fc23<<<64, B, 0, stream>>>(f1, fw2, fb2, fw3, fb3, (float*)d_out);
}